// Round 9
// baseline (180.816 us; speedup 1.0000x reference)
//
#include <hip/hip_runtime.h>
#include <hip/hip_bf16.h>

#define NN 50000
#define RR 16
#define H0 128
#define H1 64
#define EE 800000
#define NBASE 8
#define NTILES (NN / 16)            // 3125
#define NGRPS ((NTILES + 3) / 4)    // 782 groups of 64 nodes
#define GEMM_BLOCKS (NGRPS * 2)     // 8 rel-groups of 2 rels -> 6256 wave-units / 4
#define COUNT_BLOCKS ((EE + 255) / 256)  // 3125
#define NM (NN * RR)                // 800000 bins

typedef __attribute__((ext_vector_type(8))) short short8;
typedef __attribute__((ext_vector_type(4))) float f32x4;
typedef __attribute__((ext_vector_type(4))) unsigned uint4v;

__device__ inline short f2bs(float x) {
    __hip_bfloat16 b = __float2bfloat16(x);
    return *reinterpret_cast<short*>(&b);
}

// ---------------- weights = comps @ bases, bf16 transposed [r][o][k] ----------------
__global__ void k_weights(const float* __restrict__ comps, const float* __restrict__ bases,
                          __hip_bfloat16* __restrict__ wtT) {
    int idx = blockIdx.x * blockDim.x + threadIdx.x;
    if (idx >= RR * H1 * H0) return;
    int r = idx / (H1 * H0);
    int rem = idx % (H1 * H0);
    int o = rem / H0;
    int i = rem % H0;
    float acc = 0.0f;
#pragma unroll
    for (int b = 0; b < NBASE; ++b)
        acc += comps[r * NBASE + b] * bases[(b * H0 + i) * H1 + o];
    wtT[idx] = __float2bfloat16(acc);
}

// ---------------- fused: [gemm blocks] + [count+rank blocks] ----------------
// gemm: wave owns 64 nodes x 2 rels (8 rel-groups -> 2x R7's blocks for
// latency hiding). Channel-permuted B tiles; lane (n16,kg) accumulates
// channels [kg*16,kg*16+16) of node n16. nw row layout permuted so stores are
// sector-complete: q0 -> row byte kg*16, q1 -> 64+kg*16. Element index
// ((l>>3)&1)*32+(l>>4)*8+(l&7) holds channel l. Non-temporal stores.
// count: rank[e] = atomicAdd(cnt[s*16+r], 1); k_place then needs no atomics.
__global__ void k_fused(const float* __restrict__ nodes,
                        const __hip_bfloat16* __restrict__ wtT,
                        __hip_bfloat16* __restrict__ nw,
                        const int* __restrict__ src, const int* __restrict__ rel,
                        int* __restrict__ cnt, int* __restrict__ rank) {
    if (blockIdx.x < GEMM_BLOCKS) {
        int wid  = threadIdx.x >> 6;
        int lane = threadIdx.x & 63;
        int gw   = blockIdx.x * 4 + wid;         // wave-unit id
        int ngrp = gw >> 3;                      // 64-node group
        int rg   = gw & 7;                       // relation group (2 rels)
        int n16  = lane & 15;
        int kg   = lane >> 4;

        int ntl = NTILES - ngrp * 4;
        if (ntl > 4) ntl = 4;

        // A fragments: 4 tiles x 4 k-steps, f32->bf16 fused (64 VGPRs)
        short8 afrag[4][4];
#pragma unroll
        for (int t = 0; t < 4; ++t) {
            if (t < ntl) {
                const float* ap = &nodes[(size_t)((ngrp * 4 + t) * 16 + n16) * H0 + kg * 8];
#pragma unroll
                for (int ks = 0; ks < 4; ++ks) {
                    float4 lo = *(const float4*)(ap + ks * 32);
                    float4 hi = *(const float4*)(ap + ks * 32 + 4);
                    short8 a;
                    a[0] = f2bs(lo.x); a[1] = f2bs(lo.y); a[2] = f2bs(lo.z); a[3] = f2bs(lo.w);
                    a[4] = f2bs(hi.x); a[5] = f2bs(hi.y); a[6] = f2bs(hi.z); a[7] = f2bs(hi.w);
                    afrag[t][ks] = a;
                }
            }
        }

        int chb = (n16 >> 2) * 16 + (n16 & 3);   // permuted channel base for A-row n16

        for (int r0 = 0; r0 < 2; ++r0) {
            int r = rg * 2 + r0;
            const __hip_bfloat16* wrr = &wtT[((size_t)r * H1 + chb) * H0 + kg * 8];
            f32x4 acc[4][4];                     // [ot][tile]
#pragma unroll
            for (int ot = 0; ot < 4; ++ot)
#pragma unroll
                for (int t = 0; t < 4; ++t) acc[ot][t] = (f32x4){0, 0, 0, 0};

#pragma unroll
            for (int ot = 0; ot < 4; ++ot) {
#pragma unroll
                for (int ks = 0; ks < 4; ++ks) {
                    short8 w = *(const short8*)(wrr + (size_t)(ot * 4) * H0 + ks * 32);
                    acc[ot][0] = __builtin_amdgcn_mfma_f32_16x16x32_bf16(w, afrag[0][ks], acc[ot][0], 0, 0, 0);
                    acc[ot][1] = __builtin_amdgcn_mfma_f32_16x16x32_bf16(w, afrag[1][ks], acc[ot][1], 0, 0, 0);
                    acc[ot][2] = __builtin_amdgcn_mfma_f32_16x16x32_bf16(w, afrag[2][ks], acc[ot][2], 0, 0, 0);
                    acc[ot][3] = __builtin_amdgcn_mfma_f32_16x16x32_bf16(w, afrag[3][ks], acc[ot][3], 0, 0, 0);
                }
            }

            // lane holds channels kg*16 .. kg*16+15 of node (t,n16) in pk[0..7].
#pragma unroll
            for (int t = 0; t < 4; ++t) {
                if (t >= ntl) break;
                unsigned pk[8];
#pragma unroll
                for (int j = 0; j < 8; ++j) {    // pk[j] = channels kg*16+2j, +1
                    f32x4 a = acc[j >> 1][t];
                    float lo = a[(j & 1) * 2], hi = a[(j & 1) * 2 + 1];
                    pk[j] = (unsigned)(unsigned short)f2bs(lo) |
                            ((unsigned)(unsigned short)f2bs(hi) << 16);
                }
                uint4v q0 = {pk[0], pk[1], pk[2], pk[3]};
                uint4v q1 = {pk[4], pk[5], pk[6], pk[7]};
                char* rowp = (char*)nw +
                             ((size_t)r * NN + (size_t)ngrp * 64 + t * 16 + n16) * 128;
                __builtin_nontemporal_store(q0, (uint4v*)(rowp + kg * 16));
                __builtin_nontemporal_store(q1, (uint4v*)(rowp + 64 + kg * 16));
            }
        }
    } else {
        int e = (blockIdx.x - GEMM_BLOCKS) * 256 + threadIdx.x;
        if (e < EE) {
            int bin = src[e] * RR + rel[e];
            int rk = atomicAdd(&cnt[bin], 1);
            __builtin_nontemporal_store(rk, &rank[e]);
        }
    }
}

// ---------------- scan level 1: 1024 elems/block, 256 thr x int4 ----------------
__global__ void k_scan1(const int* __restrict__ cnt, int* __restrict__ base2,
                        int* __restrict__ bsums) {
    __shared__ int tmp[256];
    int tid = threadIdx.x;
    int g = blockIdx.x * 256 + tid;
    int4 v = {0, 0, 0, 0};
    if (g * 4 < NM) v = *(const int4*)&cnt[g * 4];   // NM % 4 == 0
    int s = v.x + v.y + v.z + v.w;
    tmp[tid] = s;
    __syncthreads();
    for (int off = 1; off < 256; off <<= 1) {
        int t = (tid >= off) ? tmp[tid - off] : 0;
        __syncthreads();
        tmp[tid] += t;
        __syncthreads();
    }
    int excl = tmp[tid] - s;
    if (tid == 255) bsums[blockIdx.x] = tmp[255];
    if (g * 4 < NM) {
        int4 o;
        o.x = excl;
        o.y = excl + v.x;
        o.z = excl + v.x + v.y;
        o.w = excl + v.x + v.y + v.z;
        *(int4*)&base2[g * 4] = o;
    }
}

__global__ void k_scan2(const int* __restrict__ bsums, int* __restrict__ bsofs, int nb) {
    __shared__ int tmp[1024];
    int tid = threadIdx.x;
    int v = (tid < nb) ? bsums[tid] : 0;
    tmp[tid] = v;
    __syncthreads();
    for (int off = 1; off < 1024; off <<= 1) {
        int t = (tid >= off) ? tmp[tid - off] : 0;
        __syncthreads();
        tmp[tid] += t;
        __syncthreads();
    }
    if (tid < nb) bsofs[tid] = tmp[tid] - v;
}

__global__ void k_scan3(int* __restrict__ base2, const int* __restrict__ bsofs) {
    int g = blockIdx.x * blockDim.x + threadIdx.x;
    if (g * 4 < NM) {
        int ofs = bsofs[(g * 4) >> 10];
        int4 v = *(int4*)&base2[g * 4];
        v.x += ofs; v.y += ofs; v.z += ofs; v.w += ofs;
        *(int4*)&base2[g * 4] = v;
    }
    if (g == 0) base2[NM] = EE;
}

// ---------------- place edges, NO atomics: pos = base2[bin] + rank[e] ----------------
__global__ void k_place(const int* __restrict__ src, const int* __restrict__ rel,
                        const int* __restrict__ dst, const int* __restrict__ base2,
                        const int* __restrict__ rank, unsigned* __restrict__ recs) {
    int e = blockIdx.x * blockDim.x + threadIdx.x;
    if (e < EE) {
        int s = src[e], r = rel[e];
        int pos = base2[s * RR + r] + rank[e];
        recs[pos] = ((unsigned)r << 16) | (unsigned)dst[e];
    }
}

// ---------------- per-src accumulation: one wave per src, zero atomics ----------------
// nw rows are channel-permuted: element ((l>>3)&1)*32+(l>>4)*8+(l&7) = channel l.
__global__ void k_accum(const int* __restrict__ base2, const unsigned* __restrict__ recs,
                        const __hip_bfloat16* __restrict__ nw, const float* __restrict__ bias,
                        float* __restrict__ out) {
    int s = blockIdx.x * 4 + (threadIdx.x >> 6);
    int lane = threadIdx.x & 63;
    if (s >= NN) return;
    int pl = ((lane >> 3) & 1) * 32 + (lane >> 4) * 8 + (lane & 7);  // permuted elem idx
    int b0 = base2[s * RR];
    int n  = base2[s * RR + RR] - b0;
    const int* bnd = &base2[s * RR];
    float a[8];
    a[0] = bias[lane];
#pragma unroll
    for (int j = 1; j < 8; ++j) a[j] = 0.0f;
    int i = 0;
    for (; i + 8 <= n; i += 8) {
        unsigned rc[8]; int rr[8], dd[8]; float vv[8], mm[8];
#pragma unroll
        for (int j = 0; j < 8; ++j) rc[j] = recs[b0 + i + j];
#pragma unroll
        for (int j = 0; j < 8; ++j) { rr[j] = rc[j] >> 16; dd[j] = rc[j] & 0xFFFF; }
#pragma unroll
        for (int j = 0; j < 8; ++j)
            mm[j] = __bfloat162float(nw[((size_t)rr[j] * NN + dd[j]) * H1 + pl]);
#pragma unroll
        for (int j = 0; j < 8; ++j)
            vv[j] = 1.0f / (float)(bnd[rr[j] + 1] - bnd[rr[j]]);
#pragma unroll
        for (int j = 0; j < 8; ++j) a[j] += vv[j] * mm[j];
    }
    for (; i + 2 <= n; i += 2) {
        unsigned rec0 = recs[b0 + i], rec1 = recs[b0 + i + 1];
        int r0 = rec0 >> 16, d0 = rec0 & 0xFFFF;
        int r1 = rec1 >> 16, d1 = rec1 & 0xFFFF;
        float m0 = __bfloat162float(nw[((size_t)r0 * NN + d0) * H1 + pl]);
        float m1 = __bfloat162float(nw[((size_t)r1 * NN + d1) * H1 + pl]);
        a[0] += (1.0f / (float)(bnd[r0 + 1] - bnd[r0])) * m0;
        a[1] += (1.0f / (float)(bnd[r1 + 1] - bnd[r1])) * m1;
    }
    if (i < n) {
        unsigned rec = recs[b0 + i];
        int r = rec >> 16, d = rec & 0xFFFF;
        a[0] += (1.0f / (float)(bnd[r + 1] - bnd[r])) *
                __bfloat162float(nw[((size_t)r * NN + d) * H1 + pl]);
    }
    out[(size_t)s * H1 + lane] = ((a[0] + a[1]) + (a[2] + a[3])) +
                                 ((a[4] + a[5]) + (a[6] + a[7]));
}

// ---------------- fallback (small ws) ----------------
__global__ void k_init_out(float* __restrict__ out, const float* __restrict__ bias) {
    int i = blockIdx.x * blockDim.x + threadIdx.x;
    if (i < NN * H1) out[i] = bias[i & (H1 - 1)];
}

__global__ void k_count_only(const int* __restrict__ src, const int* __restrict__ rel,
                             float* __restrict__ counts) {
    int e = blockIdx.x * blockDim.x + threadIdx.x;
    if (e < EE) atomicAdd(&counts[rel[e] * NN + src[e]], 1.0f);
}

__global__ void k_fused_edge(const int* __restrict__ src, const int* __restrict__ rel,
                             const int* __restrict__ dst, const float* __restrict__ nodes,
                             const float* __restrict__ counts,
                             const __hip_bfloat16* __restrict__ wtT, float* __restrict__ out) {
    int e = blockIdx.x * (blockDim.x >> 6) + (threadIdx.x >> 6);
    int lane = threadIdx.x & 63;
    if (e >= EE) return;
    int s = src[e], r = rel[e], d = dst[e];
    float val = 1.0f / counts[r * NN + s];
    const __hip_bfloat16* w = &wtT[(size_t)(r * H1 + lane) * H0];
    const float* nd = &nodes[(size_t)d * H0];
    float acc = 0.0f;
#pragma unroll 8
    for (int i = 0; i < H0; ++i) acc += nd[i] * __bfloat162float(w[i]);
    atomicAdd(&out[s * H1 + lane], acc * val);
}

extern "C" void kernel_launch(void* const* d_in, const int* in_sizes, int n_in,
                              void* d_out, int out_size, void* d_ws, size_t ws_size,
                              hipStream_t stream) {
    const float* nodes = (const float*)d_in[0];
    const float* comps = (const float*)d_in[1];
    const float* bases = (const float*)d_in[2];
    const float* bias  = (const float*)d_in[3];
    const int*   src   = (const int*)d_in[4];
    const int*   rel   = (const int*)d_in[5];
    const int*   dst   = (const int*)d_in[6];
    float* out = (float*)d_out;

    char* ws = (char*)d_ws;
    // ws layout (bytes), all 256-aligned, nw 128-aligned:
    //   cnt    i32 [NM]       @ 0           (3,200,000)
    //   base2  i32 [NM+1]     @ 3,200,256   (3,200,016)
    //   bsums  i32 [800]      @ 6,400,512
    //   bsofs  i32 [800]      @ 6,403,968
    //   wtT    bf16 [R*H1*H0] @ 6,407,424   (262,144)
    //   rank   i32 [EE]       @ 6,669,824   (3,200,000)
    //   recs   u32 [EE]       @ 9,870,080   (3,200,000)
    //   nw     bf16 [R*N*H1]  @ 13,070,080  (102,400,000) -> total 115,470,080
    int*   cnt           = (int*)ws;
    int*   base2         = (int*)(ws + 3200256);
    int*   bsums         = (int*)(ws + 6400512);
    int*   bsofs         = (int*)(ws + 6403968);
    __hip_bfloat16* wtT  = (__hip_bfloat16*)(ws + 6407424);
    int*   rank          = (int*)(ws + 6669824);
    unsigned* recs       = (unsigned*)(ws + 9870080);
    __hip_bfloat16* nw   = (__hip_bfloat16*)(ws + 13070080);
    const size_t need_full = 13070080ull + (size_t)RR * NN * H1 * 2ull;

    if (ws_size >= need_full) {
        const int NB_SCAN = (NM + 1023) / 1024;   // 782
        (void)hipMemsetAsync(cnt, 0, (size_t)NM * 4, stream);
        k_weights<<<(RR * H1 * H0 + 255) / 256, 256, 0, stream>>>(comps, bases, wtT);
        k_fused<<<GEMM_BLOCKS + COUNT_BLOCKS, 256, 0, stream>>>(nodes, wtT, nw, src, rel, cnt, rank);
        k_scan1<<<NB_SCAN, 256, 0, stream>>>(cnt, base2, bsums);
        k_scan2<<<1, 1024, 0, stream>>>(bsums, bsofs, NB_SCAN);
        k_scan3<<<(NM / 4 + 255) / 256, 256, 0, stream>>>(base2, bsofs);
        k_place<<<(EE + 255) / 256, 256, 0, stream>>>(src, rel, dst, base2, rank, recs);
        k_accum<<<(NN + 3) / 4, 256, 0, stream>>>(base2, recs, nw, bias, out);
    } else {
        float* countsF = (float*)ws;
        __hip_bfloat16* wtT2 = (__hip_bfloat16*)(ws + 3200256);
        (void)hipMemsetAsync(countsF, 0, (size_t)NM * 4, stream);
        k_count_only<<<(EE + 255) / 256, 256, 0, stream>>>(src, rel, countsF);
        k_weights<<<(RR * H1 * H0 + 255) / 256, 256, 0, stream>>>(comps, bases, wtT2);
        k_init_out<<<(NN * H1 + 255) / 256, 256, 0, stream>>>(out, bias);
        k_fused_edge<<<EE / 4, 256, 0, stream>>>(src, rel, dst, nodes, countsF, wtT2, out);
    }
}